// Round 6
// baseline (449.702 us; speedup 1.0000x reference)
//
#include <hip/hip_runtime.h>
#include <hip/hip_bf16.h>
#include <hip/hip_fp16.h>

// Problem constants (match reference)
#define NN 100000
#define EE 1600000
#define INF_DIM 128
#define NHEAD 4
#define HDIM 32
#define NEG_SLOPE 0.2f

typedef __attribute__((ext_vector_type(8))) short short8;
typedef __attribute__((ext_vector_type(4))) float floatx4;

__device__ __forceinline__ unsigned short f2bf(float x) {
  union { float f; unsigned int u; } c;
  c.f = x;
  const unsigned int r = c.u + 0x7fffu + ((c.u >> 16) & 1u);  // RNE
  return (unsigned short)(r >> 16);
}
__device__ __forceinline__ float bf2f(unsigned short u) {
  union { unsigned int u; float f; } c;
  c.u = ((unsigned int)u) << 16;
  return c.f;
}
// unpack packed pair of bf16 (from one u32) to two floats
__device__ __forceinline__ void bf2x(unsigned int u, float& lo, float& hi) {
  union { unsigned int u; float f; } a, b;
  a.u = u << 16;
  b.u = u & 0xffff0000u;
  lo = a.f;
  hi = b.f;
}
__device__ __forceinline__ unsigned int packh2(float a, float b) {
  const __half ha = __float2half(a), hb = __float2half(b);
  const unsigned short ua = *(const unsigned short*)&ha;
  const unsigned short ub = *(const unsigned short*)&hb;
  return (unsigned int)ua | ((unsigned int)ub << 16);
}

// ---------------------------------------------------------------------------
// MFMA GEMM: C[M,128] = A[M,128] @ W[128,128]^T (+bias), W row-major [o][k].
// A input: fp32 (Af) or bf16 (Ab). Output: bf16 (Cb) or fp32+bias (Cf).
// Block = 64 rows x 128 cols, 4 waves; K=128 staged once to LDS (bf16).
// ---------------------------------------------------------------------------
#define LDA 136

__global__ __launch_bounds__(256) void gemm_mfma(
    const float* __restrict__ Af, const unsigned short* __restrict__ Ab,
    const float* __restrict__ W, const float* __restrict__ bias,
    unsigned short* __restrict__ Cb, float* __restrict__ Cf, int M) {
  __shared__ unsigned short sA[64 * LDA];   // [m][k]
  __shared__ unsigned short sW[128 * LDA];  // [o][k] == B^T
  const int tid = threadIdx.x;
  const int m0 = blockIdx.x * 64;

  {
    const int r = tid >> 1;
    const int c0 = (tid & 1) * 64;
#pragma unroll
    for (int j = 0; j < 16; ++j) {
      const float4 v = *(const float4*)&W[r * 128 + c0 + j * 4];
      ushort4 u;
      u.x = f2bf(v.x);
      u.y = f2bf(v.y);
      u.z = f2bf(v.z);
      u.w = f2bf(v.w);
      *(ushort4*)&sW[r * LDA + c0 + j * 4] = u;
    }
  }
  {
    const int r = tid >> 2;
    const int gm = m0 + r;
    const int c0 = (tid & 3) * 32;
    if (gm < M) {
      if (Af) {
#pragma unroll
        for (int j = 0; j < 8; ++j) {
          const float4 v = *(const float4*)&Af[(size_t)gm * 128 + c0 + j * 4];
          ushort4 u;
          u.x = f2bf(v.x);
          u.y = f2bf(v.y);
          u.z = f2bf(v.z);
          u.w = f2bf(v.w);
          *(ushort4*)&sA[r * LDA + c0 + j * 4] = u;
        }
      } else {
#pragma unroll
        for (int j = 0; j < 4; ++j) {
          const uint4 v = *(const uint4*)&Ab[(size_t)gm * 128 + c0 + j * 8];
          *(uint4*)&sA[r * LDA + c0 + j * 8] = v;
        }
      }
    } else {
#pragma unroll
      for (int j = 0; j < 4; ++j) {
        uint4 z;
        z.x = z.y = z.z = z.w = 0u;
        *(uint4*)&sA[r * LDA + c0 + j * 8] = z;
      }
    }
  }
  __syncthreads();

  const int wv = tid >> 6;
  const int lane = tid & 63;
  const int l16 = lane & 15;
  const int quad = lane >> 4;

  floatx4 acc[8];
#pragma unroll
  for (int i = 0; i < 8; ++i) acc[i] = (floatx4){0.f, 0.f, 0.f, 0.f};

  const unsigned short* aRow = &sA[(wv * 16 + l16) * LDA + quad * 8];
#pragma unroll
  for (int kc = 0; kc < 4; ++kc) {
    const short8 afrag = *(const short8*)(aRow + kc * 32);
#pragma unroll
    for (int nt = 0; nt < 8; ++nt) {
      const short8 bfrag =
          *(const short8*)&sW[(nt * 16 + l16) * LDA + kc * 32 + quad * 8];
      acc[nt] =
          __builtin_amdgcn_mfma_f32_16x16x32_bf16(afrag, bfrag, acc[nt], 0, 0, 0);
    }
  }

  const int mrow = m0 + wv * 16 + quad * 4;
#pragma unroll
  for (int nt = 0; nt < 8; ++nt) {
    const int col = nt * 16 + l16;
    const float bv = Cf ? bias[col] : 0.f;
#pragma unroll
    for (int r = 0; r < 4; ++r) {
      const int gm = mrow + r;
      if (gm < M) {
        const float v = acc[nt][r];
        if (Cb)
          Cb[(size_t)gm * 128 + col] = f2bf(v);
        else
          Cf[(size_t)gm * 128 + col] = v + bv;
      }
    }
  }
}

// ---------------------------------------------------------------------------
// a_s[n,h] = dot(hb[n,h,:], att_src[h,:]); a_d likewise. One thread per (n,h).
// ---------------------------------------------------------------------------
__global__ void attn_dots(const unsigned short* __restrict__ hb,
                          const float* __restrict__ att_src,
                          const float* __restrict__ att_dst,
                          float* __restrict__ a_s, float* __restrict__ a_d) {
  const int idx = blockIdx.x * blockDim.x + threadIdx.x;  // n*4 + head
  if (idx >= NN * NHEAD) return;
  const int hd = idx & 3;
  const uint4* hp = (const uint4*)(hb + (size_t)idx * HDIM);
  const float4* as = (const float4*)(att_src + hd * HDIM);
  const float4* ad = (const float4*)(att_dst + hd * HDIM);
  float s = 0.f, d = 0.f;
#pragma unroll
  for (int q = 0; q < 4; ++q) {
    const uint4 u = hp[q];
    float v[8];
    bf2x(u.x, v[0], v[1]);
    bf2x(u.y, v[2], v[3]);
    bf2x(u.z, v[4], v[5]);
    bf2x(u.w, v[6], v[7]);
    const float4 a0 = as[q * 2], a1 = as[q * 2 + 1];
    const float4 b0 = ad[q * 2], b1 = ad[q * 2 + 1];
    s += v[0] * a0.x + v[1] * a0.y + v[2] * a0.z + v[3] * a0.w;
    s += v[4] * a1.x + v[5] * a1.y + v[6] * a1.z + v[7] * a1.w;
    d += v[0] * b0.x + v[1] * b0.y + v[2] * b0.z + v[3] * b0.w;
    d += v[4] * b1.x + v[5] * b1.y + v[6] * b1.z + v[7] * b1.w;
  }
  a_s[idx] = s;
  a_d[idx] = d;
}

// ---------------------------------------------------------------------------
// CSR build: histogram of dst, segment allocation via wave-scan + one atomic
// per wave, scatter (fused with per-edge softmax-weight precompute; emits
// 16 B records {src, fp16 w01, fp16 w23, 0}).
// ---------------------------------------------------------------------------
__global__ void hist_kernel(const int* __restrict__ dst, int* __restrict__ deg) {
  const int i = blockIdx.x * blockDim.x + threadIdx.x;
  if (i < EE) atomicAdd(&deg[dst[i]], 1);
}

__global__ __launch_bounds__(256) void alloc_kernel(const int* __restrict__ deg,
                                                    int* __restrict__ rowptr,
                                                    int* __restrict__ cur,
                                                    int* __restrict__ counter) {
  const int i = blockIdx.x * blockDim.x + threadIdx.x;
  const int lane = threadIdx.x & 63;
  const int d = (i < NN) ? deg[i] : 0;
  int s = d;
#pragma unroll
  for (int off = 1; off < 64; off <<= 1) {
    const int v = __shfl_up(s, off, 64);
    if (lane >= off) s += v;
  }
  const int total = __shfl(s, 63, 64);
  int base = 0;
  if (lane == 63) base = atomicAdd(counter, total);
  base = __shfl(base, 63, 64);
  const int p = base + s - d;
  if (i < NN) {
    rowptr[i] = p;
    cur[i] = p;
  }
}

__global__ void scatter_kernel(const int* __restrict__ src,
                               const int* __restrict__ dst,
                               const float* __restrict__ a_s,
                               const float* __restrict__ a_d,
                               int* __restrict__ cur, int4* __restrict__ ebuf) {
  const int i = blockIdx.x * blockDim.x + threadIdx.x;
  if (i >= EE) return;
  const int s = src[i];
  const int d = dst[i];
  const int p = atomicAdd(&cur[d], 1);
  const float4 as = *(const float4*)&a_s[s * 4];
  const float4 ad = *(const float4*)&a_d[d * 4];
  float4 l;
  l.x = as.x + ad.x;
  l.y = as.y + ad.y;
  l.z = as.z + ad.z;
  l.w = as.w + ad.w;
  l.x = l.x > 0.f ? l.x : NEG_SLOPE * l.x;
  l.y = l.y > 0.f ? l.y : NEG_SLOPE * l.y;
  l.z = l.z > 0.f ? l.z : NEG_SLOPE * l.z;
  l.w = l.w > 0.f ? l.w : NEG_SLOPE * l.w;
  int4 e;
  e.x = s;
  e.y = (int)packh2(__expf(l.x), __expf(l.y));
  e.z = (int)packh2(__expf(l.z), __expf(l.w));
  e.w = 0;
  ebuf[p] = e;
}

// ---------------------------------------------------------------------------
// Aggregate: one wave per destination node. Lane l pre-loads edge record
// beg+l (one dwordx4 covers 64 edges); per-edge src/weights come via
// wave-uniform __shfl (v_readlane, scalar pipe) -> gather addresses are
// register-sourced and all gathers are independent (latency-hidden).
// Lane l handles features 2l,2l+1 (head l>>4). bf16 packed output.
// ---------------------------------------------------------------------------
__global__ __launch_bounds__(256) void aggregate_kernel(
    const unsigned int* __restrict__ hbd, const float* __restrict__ a_s,
    const float* __restrict__ a_d, const float* __restrict__ bias_gat,
    const int* __restrict__ rowptr, const int* __restrict__ deg,
    const int4* __restrict__ ebuf, unsigned int* __restrict__ obd) {
  const int wave = (blockIdx.x * blockDim.x + threadIdx.x) >> 6;
  const int lane = threadIdx.x & 63;
  if (wave >= NN) return;
  const int n = wave;
  const int head = lane >> 4;

  float acc0, acc1, ds;
  {  // self loop
    float l = a_s[n * 4 + head] + a_d[n * 4 + head];
    l = l > 0.f ? l : NEG_SLOPE * l;
    const float c = __expf(l);
    float f0, f1;
    bf2x(hbd[(size_t)n * 64 + lane], f0, f1);
    acc0 = c * f0;
    acc1 = c * f1;
    ds = c;
  }
  const int beg = rowptr[n];
  const int dg = deg[n];
  for (int base = 0; base < dg; base += 64) {
    const int cnt = min(64, dg - base);
    int eX = 0, eY = 0, eZ = 0;
    if (lane < cnt) {
      const int4 e = ebuf[beg + base + lane];
      eX = e.x;
      eY = e.y;
      eZ = e.z;
    }
#pragma unroll 4
    for (int j = 0; j < cnt; ++j) {
      const int sx = __shfl(eX, j, 64);
      const int wy = __shfl(eY, j, 64);
      const int wz = __shfl(eZ, j, 64);
      const unsigned int g = hbd[(size_t)sx * 64 + lane];
      const unsigned int dwd = (head & 2) ? (unsigned int)wz : (unsigned int)wy;
      const unsigned short us = (head & 1) ? (unsigned short)(dwd >> 16)
                                           : (unsigned short)(dwd & 0xffffu);
      const __half hv = *(const __half*)&us;
      const float c = __half2float(hv);
      float f0, f1;
      bf2x(g, f0, f1);
      acc0 = fmaf(c, f0, acc0);
      acc1 = fmaf(c, f1, acc1);
      ds += c;
    }
  }
  const float inv = 1.0f / ds;
  const float2 b = *(const float2*)&bias_gat[2 * lane];
  const float v0 = acc0 * inv + b.x;
  const float v1 = acc1 * inv + b.y;
  const unsigned int r0 = f2bf(v0 > 0.f ? v0 : 0.f);
  const unsigned int r1 = f2bf(v1 > 0.f ? v1 : 0.f);
  obd[(size_t)n * 64 + lane] = r0 | (r1 << 16);
}

// ---------------------------------------------------------------------------
extern "C" void kernel_launch(void* const* d_in, const int* in_sizes, int n_in,
                              void* d_out, int out_size, void* d_ws,
                              size_t ws_size, hipStream_t stream) {
  const float* x = (const float*)d_in[0];
  const int* ei = (const int*)d_in[1];  // [2,E]: row0=src, row1=dst
  const float* W_gat = (const float*)d_in[2];
  const float* att_src = (const float*)d_in[3];
  const float* att_dst = (const float*)d_in[4];
  const float* bias_gat = (const float*)d_in[5];
  const float* W_lin = (const float*)d_in[6];
  const float* b_lin = (const float*)d_in[7];
  float* out = (float*)d_out;

  // workspace carve-up (16B aligned)
  char* ws = (char*)d_ws;
  size_t off = 0;
  unsigned short* hb = (unsigned short*)(ws + off);
  off += (size_t)NN * 128 * 2;  // 25.6 MB
  unsigned short* ob = (unsigned short*)(ws + off);
  off += (size_t)NN * 128 * 2;  // 25.6 MB
  float* a_s = (float*)(ws + off); off += (size_t)NN * 4 * 4;
  float* a_d = (float*)(ws + off); off += (size_t)NN * 4 * 4;
  int* deg = (int*)(ws + off); off += (size_t)NN * 4;
  int* rowptr = (int*)(ws + off); off += (size_t)(NN + 4) * 4;
  int* cur = (int*)(ws + off); off += (size_t)NN * 4;
  int* counter = (int*)(ws + off); off += 16;
  int4* ebuf = (int4*)(ws + off); off += (size_t)EE * 16;  // 25.6 MB

  const int* src = ei;
  const int* dst = ei + EE;

  // 1) hb = bf16(x @ W_gat^T)  [MFMA]
  gemm_mfma<<<(NN + 63) / 64, 256, 0, stream>>>(x, nullptr, W_gat, nullptr, hb,
                                                nullptr, NN);
  // 2) attention dots from bf16 features
  attn_dots<<<(NN * NHEAD + 255) / 256, 256, 0, stream>>>(hb, att_src, att_dst,
                                                          a_s, a_d);
  // 3) CSR by destination + fused edge-record precompute
  hipMemsetAsync(deg, 0, (size_t)NN * 4, stream);
  hipMemsetAsync(counter, 0, 16, stream);
  hist_kernel<<<(EE + 255) / 256, 256, 0, stream>>>(dst, deg);
  alloc_kernel<<<(NN + 255) / 256, 256, 0, stream>>>(deg, rowptr, cur, counter);
  scatter_kernel<<<(EE + 255) / 256, 256, 0, stream>>>(src, dst, a_s, a_d, cur,
                                                       ebuf);
  // 4) softmax-weighted aggregation (+bias, relu) -> bf16
  aggregate_kernel<<<(NN + 3) / 4, 256, 0, stream>>>(
      (const unsigned int*)hb, a_s, a_d, bias_gat, rowptr, deg, ebuf,
      (unsigned int*)ob);
  // 5) out = ob @ W_lin^T + b_lin  [MFMA]
  gemm_mfma<<<(NN + 63) / 64, 256, 0, stream>>>(nullptr, ob, W_lin, b_lin,
                                                nullptr, out, NN);
}